// Round 11
// baseline (249.582 us; speedup 1.0000x reference)
//
#include <hip/hip_runtime.h>

typedef __attribute__((ext_vector_type(8))) short bf16x8;
typedef __attribute__((ext_vector_type(4))) float f32x4;
typedef __attribute__((ext_vector_type(2))) unsigned int u32x2;
typedef unsigned int u32;
typedef unsigned short u16;

constexpr int Bb = 4, S = 2048, D = 1024, H = 16, DK = 64, M = Bb * S;

#if __has_builtin(__builtin_amdgcn_exp2f)
#define EXP2F __builtin_amdgcn_exp2f
#else
#define EXP2F exp2f
#endif

__device__ __forceinline__ u16 f2bf(float f) {
  u32 u = __float_as_uint(f);
  return (u16)((u + 0x7fffu + ((u >> 16) & 1u)) >> 16);
}

__device__ __forceinline__ u32 cvt_pk_bf16(float a, float b) {
  u32 r;
  asm("v_cvt_pk_bf16_f32 %0, %1, %2" : "=v"(r) : "v"(a), "v"(b));
  return r;  // lo = bf16(a), hi = bf16(b), RNE
}

__device__ __forceinline__ void gld_lds16(const u16* g, u16* l) {
  __builtin_amdgcn_global_load_lds((const __attribute__((address_space(1))) u32*)g,
                                   (__attribute__((address_space(3))) u32*)l, 16, 0, 0);
}

// merged input cast: blocks [0,4096) -> 4 weights (1M elems each),
// blocks [4096,12288) -> x (8.39M elems).
struct CastAll { const float* s[5]; u16* d[5]; float sc[5]; };
__global__ __launch_bounds__(256) void cast_all_kernel(CastAll a) {
  int bid = blockIdx.x;
  int w, off;
  if (bid < 4096) { w = bid >> 10; off = ((bid & 1023) * 256 + threadIdx.x) * 4; }
  else            { w = 4;         off = ((bid - 4096) * 256 + threadIdx.x) * 4; }
  float sc = a.sc[w];
  float4 f = *(const float4*)(a.s[w] + off);
  ushort4 o;
  o.x = f2bf(f.x * sc); o.y = f2bf(f.y * sc); o.z = f2bf(f.z * sc); o.w = f2bf(f.w * sc);
  *(ushort4*)(a.d[w] + off) = o;
}

// ---- GEMM: C[m,n] = sum_k A[m,k]*Bt[n,k]; 256x128 tile, BK=64, K=1024.
// 512 threads = 8 waves (4M x 2N), per-wave 64x64 out (acc[4][4]).
// R11: TRIPLE-buffered LDS (3 x 48KB = 144KB), ONE barrier per K-step,
// 2-step prefetch, counted vmcnt(6). Hazard logic: stage(t+2 -> buf[(t+2)%3])
// overwrites the buffer read at step t-1; every wave's step-(t-1) ds_reads
// completed before it reached barrier(t) (MFMA issue needs the lgkmcnt-
// waited data), so after barrier(t) the buffer is re-writable -- no second
// barrier needed (unlike 2-buffer, where the target was read at step t).
// vmcnt(6): at step t, outstanding = step-t loads (6, staged t-2) + step-
// t+1 loads (6, staged t-1); waiting to 6 drains exactly step-t's. t=15
// peels to vmcnt(0). K-loop fully unrolled so %3 indices are compile-time.
template <bool OUTF32>
__device__ __forceinline__ void gemm_body(const u16* __restrict__ A,
                                          const u16* __restrict__ Bt,
                                          float* __restrict__ Cf, u16* __restrict__ Cb,
                                          int m0, int n0, u16* AsB, u16* BsB) {
  constexpr int K = 1024;
  constexpr int ASZ = 256 * 64, BSZ = 128 * 64;
  const int tid = threadIdx.x, wave = tid >> 6, lane = tid & 63;
  const int quad = lane >> 4, col = lane & 15;
  const int wm = wave >> 1, wn = wave & 1;

  // staging: per-thread global srcs (advance +64/step) + per-buffer LDS dsts
  const u16* pA[4];
  u16* dA[3][4];
#pragma unroll
  for (int j = 0; j < 4; j++) {
    int gl = tid + j * 512;
    int r = gl >> 3, sl = gl & 7;
    int kof = (sl ^ (r & 7)) * 8;
    pA[j] = A + (size_t)(m0 + r) * K + kof;
#pragma unroll
    for (int bi = 0; bi < 3; bi++) dA[bi][j] = AsB + bi * ASZ + gl * 8;
  }
  const u16* pB[2];
  u16* dB[3][2];
#pragma unroll
  for (int j = 0; j < 2; j++) {
    int gl = tid + j * 512;
    int r = gl >> 3, sl = gl & 7;
    int kof = (sl ^ (r & 7)) * 8;
    pB[j] = Bt + (size_t)(n0 + r) * K + kof;
#pragma unroll
    for (int bi = 0; bi < 3; bi++) dB[bi][j] = BsB + bi * BSZ + gl * 8;
  }
  // hoisted lane-constant read bases (per buffer) + kb=1 deltas
  const u16* rdA[3][4];
  const u16* rdB[3][4];
  int dkbA[4], dkbB[4];
#pragma unroll
  for (int mi = 0; mi < 4; mi++) {
    int R = wm * 64 + mi * 16 + col;
    int c0 = (quad ^ (R & 7)) << 3;
    dkbA[mi] = ((((4 + quad) ^ (R & 7)) << 3) - c0);
#pragma unroll
    for (int bi = 0; bi < 3; bi++) rdA[bi][mi] = AsB + bi * ASZ + R * 64 + c0;
  }
#pragma unroll
  for (int ni = 0; ni < 4; ni++) {
    int R = wn * 64 + ni * 16 + col;
    int c0 = (quad ^ (R & 7)) << 3;
    dkbB[ni] = ((((4 + quad) ^ (R & 7)) << 3) - c0);
#pragma unroll
    for (int bi = 0; bi < 3; bi++) rdB[bi][ni] = BsB + bi * BSZ + R * 64 + c0;
  }

  f32x4 acc[4][4];
#pragma unroll
  for (int i = 0; i < 4; i++)
#pragma unroll
    for (int j = 0; j < 4; j++) acc[i][j] = (f32x4){0.f, 0.f, 0.f, 0.f};

  auto stage = [&](int bi) {
#pragma unroll
    for (int j = 0; j < 4; j++) { gld_lds16(pA[j], dA[bi][j]); pA[j] += 64; }
#pragma unroll
    for (int j = 0; j < 2; j++) { gld_lds16(pB[j], dB[bi][j]); pB[j] += 64; }
  };

  auto compute = [&](int bi) {
    bf16x8 af[4][2], bfr[4][2];
#pragma unroll
    for (int mi = 0; mi < 4; mi++) {
      af[mi][0] = *(const bf16x8*)(rdA[bi][mi]);
      af[mi][1] = *(const bf16x8*)(rdA[bi][mi] + dkbA[mi]);
    }
#pragma unroll
    for (int ni = 0; ni < 4; ni++) {
      bfr[ni][0] = *(const bf16x8*)(rdB[bi][ni]);
      bfr[ni][1] = *(const bf16x8*)(rdB[bi][ni] + dkbB[ni]);
    }
#pragma unroll
    for (int kb = 0; kb < 2; kb++)
#pragma unroll
      for (int mi = 0; mi < 4; mi++)
#pragma unroll
        for (int ni = 0; ni < 4; ni++)
          acc[mi][ni] = __builtin_amdgcn_mfma_f32_16x16x32_bf16(af[mi][kb], bfr[ni][kb], acc[mi][ni], 0, 0, 0);
  };

  // prologue: stage K-steps 0,1 (12 loads in flight)
  stage(0);
  stage(1);

#pragma unroll
  for (int t = 0; t < 16; t++) {
    if (t == 15) asm volatile("s_waitcnt vmcnt(0)" ::: "memory");
    else         asm volatile("s_waitcnt vmcnt(6)" ::: "memory");
    __builtin_amdgcn_sched_barrier(0);
    __builtin_amdgcn_s_barrier();  // step-t data landed for all waves; reads
    __builtin_amdgcn_sched_barrier(0);  // of buf[(t+2)%3] (step t-1) done
    if (t + 2 < 16) stage((t + 2) % 3);
    compute(t % 3);
  }

  // epilogue
#pragma unroll
  for (int mi = 0; mi < 4; mi++)
#pragma unroll
    for (int ni = 0; ni < 4; ni++)
#pragma unroll
      for (int r = 0; r < 4; r++) {
        int row = m0 + wm * 64 + mi * 16 + quad * 4 + r;
        int cc = n0 + wn * 64 + ni * 16 + col;
        float v = acc[mi][ni][r];
        if (OUTF32) Cf[(size_t)row * D + cc] = v;
        else Cb[(size_t)row * D + cc] = f2bf(v);
      }
}

struct QkvArgs { const u16* bt[3]; u16* c[3]; };
__global__ __launch_bounds__(512) void gemm_qkv(const u16* __restrict__ A, QkvArgs q) {
  __shared__ __align__(16) u16 As[3][256 * 64];
  __shared__ __align__(16) u16 Bs[3][128 * 64];
  int sel = blockIdx.x >> 3;
  int n0 = (blockIdx.x & 7) * 128, m0 = blockIdx.y * 256;
  gemm_body<false>(A, q.bt[sel], nullptr, q.c[sel], m0, n0, As[0], Bs[0]);
}

__global__ __launch_bounds__(512) void gemm_f32(const u16* __restrict__ A,
                                                const u16* __restrict__ Bt,
                                                float* __restrict__ C) {
  __shared__ __align__(16) u16 As[3][256 * 64];
  __shared__ __align__(16) u16 Bs[3][128 * 64];
  gemm_body<true>(A, Bt, C, nullptr, blockIdx.y * 256, blockIdx.x * 128, As[0], Bs[0]);
}

// ---- flash attention, causal ---- (exact R7 structure: best verified 69.4us)
__global__ __launch_bounds__(256) void attn_kernel(const u16* __restrict__ Q,
                                                   const u16* __restrict__ K,
                                                   const u16* __restrict__ V,
                                                   u16* __restrict__ O) {
  __shared__ __align__(16) u16 Ks[2][2][64 * 32];  // [buf][d-half][key*32 + swz-slot]
  __shared__ __align__(16) u16 Vt[2][64 * 64];     // [buf] V^T [d][key-swizzled]
  __shared__ __align__(16) u16 Pw[4][32 * 64];     // per-wave P [q][key-swizzled]
  const int tid = threadIdx.x, wave = tid >> 6, lane = tid & 63;
  const int quad = lane >> 4, col = lane & 15;
  const int bh = blockIdx.x, b = bh >> 4, h = bh & 15;
  const int pair = blockIdx.y;  // 0..7
  const size_t base = (size_t)b * S * D + h * DK;

  const int vk0 = (tid & 31) * 2;  // V staging: keys (vk0, vk0+1) x 8 d's
  const int vdg = tid >> 5;        // d-group 0..7

  bf16x8 bones;
#pragma unroll
  for (int e = 0; e < 8; e++) bones[e] = (short)0x3F80;  // bf16 1.0

  // ---- hoisted lane-constant LDS addresses ----
  const int rsw = col & 7;
  const int ksl = ((quad ^ ((col >> 1) & 3)) & 3) << 3;
  const u16* kbase[2] = { &Ks[0][0][col * 32 + ksl], &Ks[1][0][col * 32 + ksl] };
  const int vsl0 = ((quad ^ rsw) & 7) << 3;          // slot offsets (elements)
  const int vsl1 = (((4 + quad) ^ rsw) & 7) << 3;
  const u16* vbase[2] = { &Vt[0][col * 64], &Vt[1][col * 64] };
  u16* pww[2] = { &Pw[wave][col * 64 + (quad & 1) * 4],
                  &Pw[wave][(16 + col) * 64 + (quad & 1) * 4] };
  int swof[4];
#pragma unroll
  for (int n16 = 0; n16 < 4; n16++)
    swof[n16] = (((n16 * 2 + (quad >> 1)) ^ rsw) & 7) << 3;
  const u16* apbase[2] = { &Pw[wave][col * 64], &Pw[wave][(16 + col) * 64] };
  // K DMA lane mapping (source d-chunk pre-swizzled: chunk = slot ^ ((key>>1)&3))
  const int kk = tid >> 2;
  const int dch = (tid & 3) ^ ((kk >> 1) & 3);
  const int cb = wave * 64;
  u16* dk[2][2] = { { &Ks[0][0][cb * 8], &Ks[0][1][cb * 8] },
                    { &Ks[1][0][cb * 8], &Ks[1][1][cb * 8] } };
  // V stage write addressing
  const int kgrp = vk0 >> 3, kin = vk0 & 7;
  u16* vwb[2] = { &Vt[0][vdg * 8 * 64 + kin], &Vt[1][vdg * 8 * 64 + kin] };
  int vwof[8];
#pragma unroll
  for (int e = 0; e < 8; e++) vwof[e] = e * 64 + ((kgrp ^ e) & 7) * 8;

  auto vstage = [&](const int buf, bf16x8 r0, bf16x8 r1) {
    u16* wb = vwb[buf];
#pragma unroll
    for (int e = 0; e < 8; e++) {
      u32 val = ((u32)(u16)r0[e]) | ((u32)(u16)r1[e] << 16);
      *(u32*)(wb + vwof[e]) = val;
    }
  };

  for (int half = 0; half < 2; half++) {
    const int qb = half ? pair : 15 - pair;
    const int qw = qb * 128 + wave * 32;
    const int nkt = 2 * qb + 2;  // even

    bf16x8 aq[2][2];
#pragma unroll
    for (int mi = 0; mi < 2; mi++)
#pragma unroll
      for (int kb = 0; kb < 2; kb++)
        aq[mi][kb] = *(const bf16x8*)(Q + base + (size_t)(qw + mi * 16 + col) * D + kb * 32 + quad * 8);

    f32x4 ao[2][4], lacc[2];
#pragma unroll
    for (int mi = 0; mi < 2; mi++) {
      lacc[mi] = (f32x4){0.f, 0.f, 0.f, 0.f};
#pragma unroll
      for (int dg = 0; dg < 4; dg++) ao[mi][dg] = (f32x4){0.f, 0.f, 0.f, 0.f};
    }

    // compute body for one k-tile; BF is compile-time per unrolled body
    auto compute = [&](const int BF, int kt) {
      const u16* kbK = kbase[BF];
      bf16x8 bk0[4], bk1[4];
#pragma unroll
      for (int n16 = 0; n16 < 4; n16++) {
        bk0[n16] = *(const bf16x8*)(kbK + n16 * 512);
        bk1[n16] = *(const bf16x8*)(kbK + n16 * 512 + 2048);
      }
      f32x4 sacc[2][4];
#pragma unroll
      for (int qi = 0; qi < 2; qi++)
#pragma unroll
        for (int n16 = 0; n16 < 4; n16++) sacc[qi][n16] = (f32x4){0.f, 0.f, 0.f, 0.f};
      __builtin_amdgcn_s_setprio(1);
#pragma unroll
      for (int qi = 0; qi < 2; qi++)
#pragma unroll
        for (int n16 = 0; n16 < 4; n16++) {
          sacc[qi][n16] = __builtin_amdgcn_mfma_f32_16x16x32_bf16(bk0[n16], aq[qi][0], sacc[qi][n16], 0, 0, 0);
          sacc[qi][n16] = __builtin_amdgcn_mfma_f32_16x16x32_bf16(bk1[n16], aq[qi][1], sacc[qi][n16], 0, 0, 0);
        }
      __builtin_amdgcn_s_setprio(0);
      const bool full = (kt * 64 + 63) <= qw;  // wave-uniform: no masking
#pragma unroll
      for (int qi = 0; qi < 2; qi++) {
        const int qg = qw + qi * 16 + col;
#pragma unroll
        for (int n16 = 0; n16 < 4; n16++) {
          float p0 = EXP2F(sacc[qi][n16][0]);
          float p1 = EXP2F(sacc[qi][n16][1]);
          float p2 = EXP2F(sacc[qi][n16][2]);
          float p3 = EXP2F(sacc[qi][n16][3]);
          if (!full) {
            int kg = kt * 64 + n16 * 16 + quad * 4;
            p0 = (kg + 0 > qg) ? 0.f : p0;
            p1 = (kg + 1 > qg) ? 0.f : p1;
            p2 = (kg + 2 > qg) ? 0.f : p2;
            p3 = (kg + 3 > qg) ? 0.f : p3;
          }
          u32 lo = cvt_pk_bf16(p0, p1);
          u32 hi = cvt_pk_bf16(p2, p3);
          *(u32x2*)(pww[qi] + swof[n16]) = (u32x2){lo, hi};
        }
      }
      // PV + ones-MFMA row sums (same-wave LDS write->read, in-order DS)
      const u16* vtB = vbase[BF];
      bf16x8 bv0[4], bv1[4];
#pragma unroll
      for (int dg = 0; dg < 4; dg++) {
        bv0[dg] = *(const bf16x8*)(vtB + dg * 1024 + vsl0);
        bv1[dg] = *(const bf16x8*)(vtB + dg * 1024 + vsl1);
      }
#pragma unroll
      for (int mi = 0; mi < 2; mi++) {
        bf16x8 ap0 = *(const bf16x8*)(apbase[mi] + vsl0);
        bf16x8 ap1 = *(const bf16x8*)(apbase[mi] + vsl1);
        __builtin_amdgcn_s_setprio(1);
#pragma unroll
        for (int dg = 0; dg < 4; dg++) {
          ao[mi][dg] = __builtin_amdgcn_mfma_f32_16x16x32_bf16(ap0, bv0[dg], ao[mi][dg], 0, 0, 0);
          ao[mi][dg] = __builtin_amdgcn_mfma_f32_16x16x32_bf16(ap1, bv1[dg], ao[mi][dg], 0, 0, 0);
        }
        lacc[mi] = __builtin_amdgcn_mfma_f32_16x16x32_bf16(ap0, bones, lacc[mi], 0, 0, 0);
        lacc[mi] = __builtin_amdgcn_mfma_f32_16x16x32_bf16(ap1, bones, lacc[mi], 0, 0, 0);
        __builtin_amdgcn_s_setprio(0);
      }
    };

    // ---- prologue ----
    bf16x8 vA0, vA1, vB0, vB1;
    const u16* gv = V + base + (size_t)vk0 * D + vdg * 8;  // V tile 0
    vA0 = *(const bf16x8*)gv;
    vA1 = *(const bf16x8*)(gv + D);
    __syncthreads();  // previous half's LDS readers done before restaging
    const u16* gk = K + base + (size_t)kk * D + dch * 8;   // K tile 0
    gld_lds16(gk, dk[0][0]);
    gld_lds16(gk + 32, dk[0][1]);
    gk += (size_t)64 * D;  // -> tile 1
    vstage(0, vA0, vA1);
    vB0 = *(const bf16x8*)(gv + (size_t)64 * D);           // V tile 1
    vB1 = *(const bf16x8*)(gv + (size_t)64 * D + D);
    gv += (size_t)128 * D;  // -> tile 2

    // ---- main loop, unrolled by 2 (bf = 0 then 1, compile-time) ----
    for (int kt = 0; kt < nkt; kt += 2) {
      // even body: bf=0, stage tile kt+1 -> buf1 from vB, load vA = tile kt+2
      __syncthreads();  // drains K(kt) DMA; publishes Vt[0]
      {
        // kt+1 < nkt always (nkt even)
        gld_lds16(gk, dk[1][0]);
        gld_lds16(gk + 32, dk[1][1]);
        gk += (size_t)64 * D;
        vstage(1, vB0, vB1);
        if (kt + 2 < nkt) {
          vA0 = *(const bf16x8*)gv;
          vA1 = *(const bf16x8*)(gv + D);
          gv += (size_t)64 * D;
        }
        if (kt * 64 <= qw + 31) compute(0, kt);
      }
      // odd body: bf=1, stage tile kt+2 -> buf0 from vA, load vB = tile kt+3
      __syncthreads();  // drains K(kt+1) DMA; publishes Vt[1]
      {
        const int kt1 = kt + 1;
        if (kt1 + 1 < nkt) {
          gld_lds16(gk, dk[0][0]);
          gld_lds16(gk + 32, dk[0][1]);
          gk += (size_t)64 * D;
          vstage(0, vA0, vA1);
          if (kt1 + 2 < nkt) {
            vB0 = *(const bf16x8*)gv;
            vB1 = *(const bf16x8*)(gv + D);
            gv += (size_t)64 * D;
          }
        }
        if (kt1 * 64 <= qw + 31) compute(1, kt1);
      }
    }
    // epilogue: normalize + write O
#pragma unroll
    for (int mi = 0; mi < 2; mi++)
#pragma unroll
      for (int r = 0; r < 4; r++) {
        float inv = 1.f / lacc[mi][r];
        int q = qw + mi * 16 + quad * 4 + r;
#pragma unroll
        for (int dg = 0; dg < 4; dg++)
          O[base + (size_t)q * D + dg * 16 + col] = f2bf(ao[mi][dg][r] * inv);
      }
  }
}

extern "C" void kernel_launch(void* const* d_in, const int* in_sizes, int n_in,
                              void* d_out, int out_size, void* d_ws, size_t ws_size,
                              hipStream_t stream) {
  const float* x  = (const float*)d_in[0];
  const float* Wq = (const float*)d_in[1];
  const float* Wk = (const float*)d_in[2];
  const float* Wv = (const float*)d_in[3];
  const float* Wo = (const float*)d_in[4];

  u16* xb  = (u16*)d_ws;
  u16* wqb = xb + (size_t)M * D;
  u16* wkb = wqb + (size_t)D * D;
  u16* wvb = wkb + (size_t)D * D;
  u16* wob = wvb + (size_t)D * D;
  u16* Qb  = wob + (size_t)D * D;
  u16* Kb  = Qb + (size_t)M * D;
  u16* Vb  = Kb + (size_t)M * D;
  u16* Ab  = xb;  // x dead after projections

  CastAll ca;
  ca.s[0] = Wq; ca.s[1] = Wk; ca.s[2] = Wv; ca.s[3] = Wo; ca.s[4] = x;
  ca.d[0] = wqb; ca.d[1] = wkb; ca.d[2] = wvb; ca.d[3] = wob; ca.d[4] = xb;
  ca.sc[0] = 0.18033688011112042f;  // 0.125 * log2(e) folded into Wq
  ca.sc[1] = 1.f; ca.sc[2] = 1.f; ca.sc[3] = 1.f; ca.sc[4] = 1.f;
  cast_all_kernel<<<4096 + M * D / 1024, 256, 0, stream>>>(ca);

  QkvArgs qa;
  qa.bt[0] = wqb; qa.bt[1] = wkb; qa.bt[2] = wvb;
  qa.c[0] = Qb; qa.c[1] = Kb; qa.c[2] = Vb;
  gemm_qkv<<<dim3(24, M / 256), 512, 0, stream>>>(xb, qa);

  attn_kernel<<<dim3(Bb * H, 8), 256, 0, stream>>>(Qb, Kb, Vb, Ab);

  gemm_f32<<<dim3(D / 128, M / 256), 512, 0, stream>>>(Ab, wob, (float*)d_out);
}